// Round 12
// baseline (2164.831 us; speedup 1.0000x reference)
//
#include <hip/hip_runtime.h>

// RecurrentNEFLayer on MI355X — persistent-kernel scan.
// r12: ZERO atomics in the steady-state loop.
// 128 blocks = 16 batch-groups (16 rows) x 8 neuron-groups (256 neurons).
// Per step: each block plain-stores its f32 partial s_{t+1} (16x128) into a
// private ping-pong slot; posts a per-block FLAG (plain store, no RMW);
// consumers poll the 8 flags (one 32B wave load) and read+reduce all 8 slots
// locally during s-staging. Eliminates the same-address RMW serialization
// tail that r11 measured (~0.3us per halving) and the counter RMW chain.
// Encoders LDS-resident bf16; state_decoders in registers (r11-proven).
// All cross-block data moves via relaxed agent atomic loads/stores (HW-proven
// visibility protocol from r5/r6/r11: no cache-maintenance fences needed).

constexpr int CB   = 256;   // batch
constexpr int CT   = 512;   // time steps
constexpr int DIN  = 128;
constexpr int DST  = 128;
constexpr int DOUT = 64;
constexpr int DAUG = 256;   // DIN + DST

constexpr int NBG = 16;     // batch groups
constexpr int NNG = 8;      // neuron groups (blocks per barrier group)
constexpr int BT  = 16;     // batch rows per group
constexpr int NT  = 256;    // neurons per block

constexpr int EPAD = 264;   // 256 + 8 bf16 pad
constexpr int APAD = 264;   // 256 + 8 bf16 pad (A is [b][n], n=256)

using f32x4  = __attribute__((ext_vector_type(4))) float;
using bf16x8 = __attribute__((ext_vector_type(8))) short;   // 8 bf16 in 4 VGPRs

__device__ __forceinline__ short f2b(float x) {   // f32 -> bf16 RNE
  unsigned u = __builtin_bit_cast(unsigned, x);
  u += 0x7fffu + ((u >> 16) & 1u);
  return (short)(u >> 16);
}
__device__ __forceinline__ short4 f2b4(float4 v) {
  return make_short4(f2b(v.x), f2b(v.y), f2b(v.z), f2b(v.w));
}

// workspace layout
//   Pbuf  f32 [2][16][8][16][128]  = 2 MB   (partial s, ping-pong by step parity)
//   Pflag u32 [2][16][64]          = 8 KB   (8 flags per group, 256B-strided groups)
constexpr size_t PBUF_ELEMS  = (size_t)2 * NBG * NNG * BT * DST;
constexpr int    SLOT        = BT * DST;          // 2048 f32 per block slot

__global__ void nef_init(float* Pbuf, unsigned int* Pflag, float* out) {
  int idx = blockIdx.x * blockDim.x + threadIdx.x;
  int stride = gridDim.x * blockDim.x;
  for (int i = idx; i < 2 * NBG * 64; i += stride) Pflag[i] = 0u;
  for (int i = idx; i < CB * DOUT; i += stride) out[i] = 0.f;
  (void)Pbuf;   // never read before fully overwritten
}

__global__ void __launch_bounds__(256) nef_main(
    const float* __restrict__ seq,  const float* __restrict__ enc,
    const float* __restrict__ gainp,const float* __restrict__ biasp,
    const float* __restrict__ sdec, const float* __restrict__ dec,
    float* __restrict__ out, float* __restrict__ Pbuf, unsigned int* Pflag)
{
  __shared__ short E_lds[NT][EPAD];     // encoders tile  [n][k_aug]   135.2 KB
  __shared__ short X_lds[BT][EPAD];     // [u_t | s_t]    [b][k_aug]     8.4 KB
  __shared__ short A_lds[BT][APAD];     // activations    [b][n]         8.4 KB
  __shared__ float gain_lds[NT];
  __shared__ float bias_lds[NT];

  const int tid  = threadIdx.x;
  const int bg   = blockIdx.x & 15;   // group's 8 blocks spread; flags/data via MALL
  const int ng   = blockIdx.x >> 4;
  const int b0   = bg * BT;
  const int n0   = ng * NT;
  const int wave = tid >> 6;
  const int lane = tid & 63;
  const int l15  = lane & 15;
  const int lhi  = lane >> 4;         // 0..3
  const int kbase = lhi * 8;

  // ---- one-time: stage encoders into LDS (bf16): 256 rows x 256 cols f32 ----
  for (int i = 0; i < 64; ++i) {
    int fidx = i * 256 + tid;
    int row = fidx >> 6, c4 = fidx & 63;
    const float4 v = *(const float4*)(enc + (size_t)(n0 + row) * DAUG + (c4 << 2));
    *(short4*)&E_lds[row][c4 << 2] = f2b4(v);
  }
  gain_lds[tid] = gainp[n0 + tid];    // NT == blockDim == 256
  bias_lds[tid] = biasp[n0 + tid];

  // ---- one-time: gather state_decoders^T fragments into REGISTERS ----
  bf16x8 sdt0[8], sdt1[8];
#pragma unroll
  for (int kk = 0; kk < 8; ++kk) {
    bf16x8 f0, f1;
    const int dA = wave * 32 + l15, dB = dA + 16;
#pragma unroll
    for (int j = 0; j < 8; ++j) {
      const size_t nrow = (size_t)(n0 + kk * 32 + kbase + j) * DST;
      f0[j] = f2b(sdec[nrow + dA]);
      f1[j] = f2b(sdec[nrow + dB]);
    }
    sdt0[kk] = f0; sdt1[kk] = f1;
  }

  const int nsub = wave * 64;           // wave's 64-neuron range in GEMM A

  // ---- prologue: load u_0, stage X u-half, prefetch u_1 ----
  float4 pu[2];
#pragma unroll
  for (int i = 0; i < 2; ++i) {
    int fidx = i * 256 + tid;
    int row = fidx >> 5, c4 = fidx & 31;
    pu[i] = *(const float4*)(seq + ((size_t)(b0 + row) * CT + 0) * DIN + (c4 << 2));
  }
#pragma unroll
  for (int i = 0; i < 2; ++i) {
    int fidx = i * 256 + tid;
    int row = fidx >> 5, c4 = fidx & 31;
    *(short4*)&X_lds[row][c4 << 2] = f2b4(pu[i]);
    pu[i] = *(const float4*)(seq + ((size_t)(b0 + row) * CT + 1) * DIN + (c4 << 2));
  }
  __syncthreads();   // weights + u_0 staged

  for (int t = 0; t < CT; ++t) {
    // ---- GEMM A u-half (kk 0..3): s-independent pre-poll work ----
    f32x4 acc0 = {0,0,0,0}, acc1 = {0,0,0,0}, acc2 = {0,0,0,0}, acc3 = {0,0,0,0};
#pragma unroll
    for (int kk = 0; kk < 4; ++kk) {
      bf16x8 a = *(const bf16x8*)&X_lds[l15][kk * 32 + kbase];
      bf16x8 e0 = *(const bf16x8*)&E_lds[nsub +      l15][kk * 32 + kbase];
      bf16x8 e1 = *(const bf16x8*)&E_lds[nsub + 16 + l15][kk * 32 + kbase];
      bf16x8 e2 = *(const bf16x8*)&E_lds[nsub + 32 + l15][kk * 32 + kbase];
      bf16x8 e3 = *(const bf16x8*)&E_lds[nsub + 48 + l15][kk * 32 + kbase];
      acc0 = __builtin_amdgcn_mfma_f32_16x16x32_bf16(a, e0, acc0, 0, 0, 0);
      acc1 = __builtin_amdgcn_mfma_f32_16x16x32_bf16(a, e1, acc1, 0, 0, 0);
      acc2 = __builtin_amdgcn_mfma_f32_16x16x32_bf16(a, e2, acc2, 0, 0, 0);
      acc3 = __builtin_amdgcn_mfma_f32_16x16x32_bf16(a, e3, acc3, 0, 0, 0);
    }

    // ---- stage s-half of X ----
    if (t == 0) {
      // s_0 = 0
      int row = tid >> 4, c8 = tid & 15;
      *(short4*)&X_lds[row][DIN + c8 * 8]     = make_short4(0, 0, 0, 0);
      *(short4*)&X_lds[row][DIN + c8 * 8 + 4] = make_short4(0, 0, 0, 0);
    } else {
      // poll the 8 flags (one 32B wave-coalesced load per iteration)
      {
        const unsigned int* fl = Pflag + ((size_t)(t & 1) * NBG + bg) * 64;
        unsigned int guard = 0;
        for (;;) {
          unsigned v = (lane < NNG)
              ? __hip_atomic_load(&fl[lane], __ATOMIC_RELAXED, __HIP_MEMORY_SCOPE_AGENT)
              : (unsigned)t;
          if (__all(v == (unsigned)t)) break;
          __builtin_amdgcn_s_sleep(1);
          if (++guard > 100000u) break;   // bounded: wrong answer, never a wedge
        }
      }
      // read all 8 partial slots, reduce 8-way, cvt bf16 -> X s-half
      const float* Pb = Pbuf + ((size_t)(t & 1) * NBG + bg) * (NNG * SLOT);
      int row = tid >> 4, c8 = tid & 15;           // 16 rows x 16 chunks of 8 f32
      float r0=0,r1=0,r2=0,r3=0,r4=0,r5=0,r6=0,r7=0;
#pragma unroll
      for (int s = 0; s < NNG; ++s) {
        const unsigned long long* p =
            (const unsigned long long*)(Pb + (size_t)s * SLOT + row * DST + c8 * 8);
        unsigned long long w0 = __hip_atomic_load(p + 0, __ATOMIC_RELAXED, __HIP_MEMORY_SCOPE_AGENT);
        unsigned long long w1 = __hip_atomic_load(p + 1, __ATOMIC_RELAXED, __HIP_MEMORY_SCOPE_AGENT);
        unsigned long long w2 = __hip_atomic_load(p + 2, __ATOMIC_RELAXED, __HIP_MEMORY_SCOPE_AGENT);
        unsigned long long w3 = __hip_atomic_load(p + 3, __ATOMIC_RELAXED, __HIP_MEMORY_SCOPE_AGENT);
        r0 += __builtin_bit_cast(float, (unsigned)(w0 & 0xffffffffu));
        r1 += __builtin_bit_cast(float, (unsigned)(w0 >> 32));
        r2 += __builtin_bit_cast(float, (unsigned)(w1 & 0xffffffffu));
        r3 += __builtin_bit_cast(float, (unsigned)(w1 >> 32));
        r4 += __builtin_bit_cast(float, (unsigned)(w2 & 0xffffffffu));
        r5 += __builtin_bit_cast(float, (unsigned)(w2 >> 32));
        r6 += __builtin_bit_cast(float, (unsigned)(w3 & 0xffffffffu));
        r7 += __builtin_bit_cast(float, (unsigned)(w3 >> 32));
      }
      *(short4*)&X_lds[row][DIN + c8 * 8]     = make_short4(f2b(r0), f2b(r1), f2b(r2), f2b(r3));
      *(short4*)&X_lds[row][DIN + c8 * 8 + 4] = make_short4(f2b(r4), f2b(r5), f2b(r6), f2b(r7));
    }
    __syncthreads();   // (1) s-half of X visible

    // ---- GEMM A s-half (kk 4..7) ----
#pragma unroll
    for (int kk = 4; kk < 8; ++kk) {
      bf16x8 a = *(const bf16x8*)&X_lds[l15][kk * 32 + kbase];
      bf16x8 e0 = *(const bf16x8*)&E_lds[nsub +      l15][kk * 32 + kbase];
      bf16x8 e1 = *(const bf16x8*)&E_lds[nsub + 16 + l15][kk * 32 + kbase];
      bf16x8 e2 = *(const bf16x8*)&E_lds[nsub + 32 + l15][kk * 32 + kbase];
      bf16x8 e3 = *(const bf16x8*)&E_lds[nsub + 48 + l15][kk * 32 + kbase];
      acc0 = __builtin_amdgcn_mfma_f32_16x16x32_bf16(a, e0, acc0, 0, 0, 0);
      acc1 = __builtin_amdgcn_mfma_f32_16x16x32_bf16(a, e1, acc1, 0, 0, 0);
      acc2 = __builtin_amdgcn_mfma_f32_16x16x32_bf16(a, e2, acc2, 0, 0, 0);
      acc3 = __builtin_amdgcn_mfma_f32_16x16x32_bf16(a, e3, acc3, 0, 0, 0);
    }
    {   // epilogue: relu(gain*x + bias) -> bf16 a-tile in LDS
      const int nc0 = nsub + l15, nc1 = nc0 + 16, nc2 = nc0 + 32, nc3 = nc0 + 48;
      const float g0 = gain_lds[nc0], bi0 = bias_lds[nc0];
      const float g1 = gain_lds[nc1], bi1 = bias_lds[nc1];
      const float g2 = gain_lds[nc2], bi2 = bias_lds[nc2];
      const float g3 = gain_lds[nc3], bi3 = bias_lds[nc3];
#pragma unroll
      for (int j = 0; j < 4; ++j) {   // C/D: col=lane&15, row=(lane>>4)*4+j
        A_lds[lhi * 4 + j][nc0] = f2b(fmaxf(g0 * acc0[j] + bi0, 0.f));
        A_lds[lhi * 4 + j][nc1] = f2b(fmaxf(g1 * acc1[j] + bi1, 0.f));
        A_lds[lhi * 4 + j][nc2] = f2b(fmaxf(g2 * acc2[j] + bi2, 0.f));
        A_lds[lhi * 4 + j][nc3] = f2b(fmaxf(g3 * acc3[j] + bi3, 0.f));
      }
    }
    __syncthreads();   // (2) A_lds ready; X free to overwrite

    if (t != CT - 1) {
      // ---- GEMM B: (16 x 256) @ (256 x 128) -> partial s_{t+1};
      //      B-operand from registers (sdt0/sdt1) ----
      f32x4 p0 = {0,0,0,0}, p1 = {0,0,0,0};
#pragma unroll
      for (int kk = 0; kk < 8; ++kk) {
        bf16x8 a = *(const bf16x8*)&A_lds[l15][kk * 32 + kbase];
        p0 = __builtin_amdgcn_mfma_f32_16x16x32_bf16(a, sdt0[kk], p0, 0, 0, 0);
        p1 = __builtin_amdgcn_mfma_f32_16x16x32_bf16(a, sdt1[kk], p1, 0, 0, 0);
      }
      // ---- plain relaxed agent stores into this block's private slot ----
      float* Pw = Pbuf + ((size_t)((t + 1) & 1) * NBG + bg) * (NNG * SLOT)
                       + (size_t)ng * SLOT;
      const int dA = wave * 32 + l15, dB = dA + 16;
#pragma unroll
      for (int j = 0; j < 4; ++j) {
        __hip_atomic_store(&Pw[(lhi * 4 + j) * DST + dA], p0[j],
                           __ATOMIC_RELAXED, __HIP_MEMORY_SCOPE_AGENT);
        __hip_atomic_store(&Pw[(lhi * 4 + j) * DST + dB], p1[j],
                           __ATOMIC_RELAXED, __HIP_MEMORY_SCOPE_AGENT);
      }
      // ---- stage u_{t+1} into X u-half (LDS work overlaps the store drain) ----
#pragma unroll
      for (int i = 0; i < 2; ++i) {
        int fidx = i * 256 + tid;
        int row = fidx >> 5, c4 = fidx & 31;
        *(short4*)&X_lds[row][c4 << 2] = f2b4(pu[i]);
      }
      __syncthreads();   // (3) drains partial stores (vmcnt) + u-stage LDS writes
      if (tid == 0)      // per-block flag: plain store, no RMW
        __hip_atomic_store(&Pflag[((size_t)((t + 1) & 1) * NBG + bg) * 64 + ng],
                           (unsigned)(t + 1),
                           __ATOMIC_RELAXED, __HIP_MEMORY_SCOPE_AGENT);
      // ---- off-path: issue u_{t+2} prefetch ----
      if (t + 2 < CT) {
#pragma unroll
        for (int i = 0; i < 2; ++i) {
          int fidx = i * 256 + tid;
          int row = fidx >> 5, c4 = fidx & 31;
          pu[i] = *(const float4*)(seq + ((size_t)(b0 + row) * CT + (t + 2)) * DIN + (c4 << 2));
        }
      }
    } else {
      // ---- final step: out partial = a_final @ decoders[n0:n0+256] ----
      f32x4 o0 = {0,0,0,0};
      const int ocol = wave * 16 + l15;   // 4 waves x 16 = DOUT
#pragma unroll
      for (int kk = 0; kk < 8; ++kk) {
        bf16x8 a = *(const bf16x8*)&A_lds[l15][kk * 32 + kbase];
        bf16x8 bfD;
#pragma unroll
        for (int j = 0; j < 8; ++j)
          bfD[j] = f2b(dec[(size_t)(n0 + kk * 32 + kbase + j) * DOUT + ocol]);
        o0 = __builtin_amdgcn_mfma_f32_16x16x32_bf16(a, bfD, o0, 0, 0, 0);
      }
#pragma unroll
      for (int j = 0; j < 4; ++j)         // one-time 8-way K-split reduction
        unsafeAtomicAdd(&out[(size_t)(b0 + lhi * 4 + j) * DOUT + ocol], o0[j]);
    }
  }
}

extern "C" void kernel_launch(void* const* d_in, const int* in_sizes, int n_in,
                              void* d_out, int out_size, void* d_ws, size_t ws_size,
                              hipStream_t stream) {
  const float* seq   = (const float*)d_in[0];
  const float* enc   = (const float*)d_in[1];
  const float* gainp = (const float*)d_in[2];
  const float* biasp = (const float*)d_in[3];
  const float* sdec  = (const float*)d_in[4];
  const float* dec   = (const float*)d_in[5];
  float* out = (float*)d_out;

  // workspace: Pbuf f32 2 MB | Pflag 8 KB
  float* Pbuf = (float*)d_ws;
  unsigned int* Pflag = (unsigned int*)((char*)d_ws + PBUF_ELEMS * sizeof(float));

  nef_init<<<128, 256, 0, stream>>>(Pbuf, Pflag, out);
  nef_main<<<dim3(NBG * NNG), dim3(256), 0, stream>>>(seq, enc, gainp, biasp,
                                                      sdec, dec, out, Pbuf, Pflag);
}